// Round 5
// baseline (246.339 us; speedup 1.0000x reference)
//
#include <hip/hip_runtime.h>
#include <hip/hip_bf16.h>
#include <math.h>

// Problem: B=4096, N=200, D=128, V=100000
//   h = gelu(x @ W_mu + b_mu)
//   logits[b][n] = dot(h[b], emb[cand[b][n]]) + mu_bias[cand[b][n]]
//
// Round-4 data: forward gather = 64us, FETCH=199MB @3.3TB/s (41% peak), VALU 10%.
// Random 512B fetches past L2 are the bottleneck. This round: invert the
// gather — bin pairs by vocab id, stream emb sequentially, gather L2-resident h.

#define BDIM 4096
#define NCAND 200
#define DDIM 128
#define VOCAB 100000
#define NPAIRS (BDIM * NCAND)          // 819200
#define NSB ((VOCAB + 1023) / 1024)    // scan blocks: 98

typedef unsigned int u32;

// ---------------- Kernel A: h = gelu(x @ W + b) ----------------
__global__ __launch_bounds__(256) void gelu_head_kernel(
    const float* __restrict__ x, const float* __restrict__ W,
    const float* __restrict__ bvec, float* __restrict__ h) {
  __shared__ float xs[8][DDIM];
  const int b0 = blockIdx.x * 8;
  const int t = threadIdx.x;
  {
    const float4* xg = reinterpret_cast<const float4*>(x + (size_t)b0 * DDIM);
    float4* xsv = reinterpret_cast<float4*>(&xs[0][0]);
    xsv[t] = xg[t];
  }
  __syncthreads();
  const int col = t & 127;
  const int rp = t >> 7;
  float acc0 = 0.f, acc1 = 0.f, acc2 = 0.f, acc3 = 0.f;
#pragma unroll 8
  for (int k = 0; k < DDIM; ++k) {
    const float w = W[k * DDIM + col];
    acc0 = fmaf(xs[rp + 0][k], w, acc0);
    acc1 = fmaf(xs[rp + 2][k], w, acc1);
    acc2 = fmaf(xs[rp + 4][k], w, acc2);
    acc3 = fmaf(xs[rp + 6][k], w, acc3);
  }
  const float bb = bvec[col];
  float v[4] = {acc0 + bb, acc1 + bb, acc2 + bb, acc3 + bb};
#pragma unroll
  for (int r = 0; r < 4; ++r) {
    const float u = v[r];
    const float g = 0.5f * u * (1.0f + erff(u * 0.70710678118654752f));
    h[(size_t)(b0 + rp + 2 * r) * DDIM + col] = g;
  }
}

// ---------------- Binning pipeline ----------------
__global__ __launch_bounds__(256) void hist_kernel(const int* __restrict__ cand,
                                                   u32* __restrict__ counts) {
  const int i = blockIdx.x * 256 + threadIdx.x;
  if (i < NPAIRS) atomicAdd(&counts[cand[i]], 1u);
}

// block-local exclusive scan: 1024 elems/block (4 per thread)
__global__ __launch_bounds__(256) void scan1_kernel(const u32* __restrict__ counts,
                                                    u32* __restrict__ offsets,
                                                    u32* __restrict__ partials) {
  __shared__ u32 sh[256];
  const int tid = threadIdx.x;
  const int base = blockIdx.x * 1024 + tid * 4;
  u32 v0 = (base + 0 < VOCAB) ? counts[base + 0] : 0u;
  u32 v1 = (base + 1 < VOCAB) ? counts[base + 1] : 0u;
  u32 v2 = (base + 2 < VOCAB) ? counts[base + 2] : 0u;
  u32 v3 = (base + 3 < VOCAB) ? counts[base + 3] : 0u;
  const u32 s = v0 + v1 + v2 + v3;
  sh[tid] = s;
  __syncthreads();
  for (int off = 1; off < 256; off <<= 1) {
    const u32 t = (tid >= off) ? sh[tid - off] : 0u;
    __syncthreads();
    sh[tid] += t;
    __syncthreads();
  }
  u32 excl = sh[tid] - s; // exclusive prefix of this thread's group
  if (tid == 255) partials[blockIdx.x] = sh[255];
  if (base + 0 < VOCAB) offsets[base + 0] = excl;
  excl += v0;
  if (base + 1 < VOCAB) offsets[base + 1] = excl;
  excl += v1;
  if (base + 2 < VOCAB) offsets[base + 2] = excl;
  excl += v2;
  if (base + 3 < VOCAB) offsets[base + 3] = excl;
}

// exclusive scan of the 98 block partials (single block)
__global__ __launch_bounds__(256) void scan2_kernel(u32* __restrict__ partials) {
  __shared__ u32 sh[256];
  const int tid = threadIdx.x;
  const u32 p = (tid < NSB) ? partials[tid] : 0u;
  sh[tid] = p;
  __syncthreads();
  for (int off = 1; off < 256; off <<= 1) {
    const u32 t = (tid >= off) ? sh[tid - off] : 0u;
    __syncthreads();
    sh[tid] += t;
    __syncthreads();
  }
  if (tid < NSB) partials[tid] = sh[tid] - p; // exclusive
}

// add block offsets; init cursors; write offsets[V]
__global__ __launch_bounds__(256) void scan_add_kernel(u32* __restrict__ offsets,
                                                       const u32* __restrict__ partials,
                                                       u32* __restrict__ cursors) {
  const int i = blockIdx.x * 256 + threadIdx.x;
  if (i < VOCAB) {
    const u32 v = offsets[i] + partials[i >> 10];
    offsets[i] = v;
    cursors[i] = v;
  }
  if (i == VOCAB) offsets[VOCAB] = (u32)NPAIRS;
}

__global__ __launch_bounds__(256) void scatter_kernel(const int* __restrict__ cand,
                                                      u32* __restrict__ cursors,
                                                      u32* __restrict__ pairs) {
  const int i = blockIdx.x * 256 + threadIdx.x;
  if (i < NPAIRS) {
    const u32 c = (u32)cand[i];
    const u32 pos = atomicAdd(&cursors[c], 1u);
    pairs[pos] = (u32)i;
  }
}

// ---------------- Main: one wave per vocab row ----------------
// emb row + bias read sequentially (streamed); h rows are L2-resident (2MB).
__global__ __launch_bounds__(256) void vocab_dot_kernel(
    const float* __restrict__ h, const float* __restrict__ emb,
    const float* __restrict__ bias, const u32* __restrict__ offsets,
    const u32* __restrict__ pairs, float* __restrict__ out) {
  const int wid = (blockIdx.x * 256 + threadIdx.x) >> 6;
  if (wid >= VOCAB) return;
  const int lane = threadIdx.x & 63;
  const int l16 = lane & 15;
  const int grp = lane >> 4;

  const float4* ev = reinterpret_cast<const float4*>(emb + (size_t)wid * DDIM);
  const float4 e1 = ev[l16];
  const float4 e2 = ev[l16 + 16];
  const float bv = bias[wid];
  const u32 start = offsets[wid];
  const u32 end = offsets[wid + 1];

  for (u32 j0 = start; j0 < end; j0 += 4) {
    const u32 jj = j0 + (u32)grp;
    const bool m = jj < end;
    const u32 idx = pairs[m ? jj : (end - 1)];
    const u32 b = idx / 200u; // magic-multiply division
    const float4* hv = reinterpret_cast<const float4*>(h + (size_t)b * DDIM);
    const float4 h1 = hv[l16];
    const float4 h2 = hv[l16 + 16];
    float acc = e1.x * h1.x;
    acc = fmaf(e1.y, h1.y, acc);
    acc = fmaf(e1.z, h1.z, acc);
    acc = fmaf(e1.w, h1.w, acc);
    acc = fmaf(e2.x, h2.x, acc);
    acc = fmaf(e2.y, h2.y, acc);
    acc = fmaf(e2.z, h2.z, acc);
    acc = fmaf(e2.w, h2.w, acc);
    acc += __shfl_xor(acc, 1);
    acc += __shfl_xor(acc, 2);
    acc += __shfl_xor(acc, 4);
    acc += __shfl_xor(acc, 8);
    if (l16 == 0 && m) out[idx] = acc + bv;
  }
}

// ---------------- Fallback: round-4 proven gather path ----------------
__global__ __launch_bounds__(256) void gather_dot_kernel(
    const float* __restrict__ h, const int* __restrict__ cand,
    const float* __restrict__ bias, const float* __restrict__ emb,
    float* __restrict__ out) {
  const int wave = (blockIdx.x * 256 + threadIdx.x) >> 6;
  const int lane = threadIdx.x & 63;
  const int b = wave >> 1;
  const int half = wave & 1;
  const int l16 = lane & 15;
  const int grp = lane >> 4;
  const float4* hv = reinterpret_cast<const float4*>(h + (size_t)b * DDIM);
  const float4 h1 = hv[l16];
  const float4 h2 = hv[l16 + 16];
  const int nstart = half * 100;
  const int nend = nstart + 100;
  const int rowbase = b * NCAND;
  for (int n0 = nstart; n0 < nend; n0 += 64) {
    const int nseg = min(64, nend - n0);
    int ci = 0;
    float bi = 0.f;
    if (lane < nseg) {
      ci = cand[rowbase + n0 + lane];
      bi = bias[ci];
    }
    const int iters = nseg >> 2;
#pragma unroll 4
    for (int i = 0; i < iters; ++i) {
      const int slot = i * 4 + grp;
      const int c = __shfl(ci, slot);
      const float4* ev = reinterpret_cast<const float4*>(emb + (size_t)c * DDIM);
      const float4 v1 = ev[l16];
      const float4 v2 = ev[l16 + 16];
      float acc = v1.x * h1.x;
      acc = fmaf(v1.y, h1.y, acc);
      acc = fmaf(v1.z, h1.z, acc);
      acc = fmaf(v1.w, h1.w, acc);
      acc = fmaf(v2.x, h2.x, acc);
      acc = fmaf(v2.y, h2.y, acc);
      acc = fmaf(v2.z, h2.z, acc);
      acc = fmaf(v2.w, h2.w, acc);
      acc += __shfl_xor(acc, 1);
      acc += __shfl_xor(acc, 2);
      acc += __shfl_xor(acc, 4);
      acc += __shfl_xor(acc, 8);
      const float bslot = __shfl(bi, slot);
      if (l16 == 0) out[rowbase + n0 + slot] = acc + bslot;
    }
  }
}

extern "C" void kernel_launch(void* const* d_in, const int* in_sizes, int n_in,
                              void* d_out, int out_size, void* d_ws, size_t ws_size,
                              hipStream_t stream) {
  const float* x = (const float*)d_in[0];
  const int* candidates = (const int*)d_in[1];
  const float* W_mu = (const float*)d_in[2];
  const float* b_mu = (const float*)d_in[3];
  const float* mu_bias = (const float*)d_in[4];
  const float* emb_table = (const float*)d_in[5];
  float* out = (float*)d_out;

  // workspace layout (256B-aligned chunks)
  char* ws = (char*)d_ws;
  size_t off = 0;
  float* h = (float*)(ws + off);
  off += (size_t)BDIM * DDIM * 4;                    // 2,097,152
  u32* counts = (u32*)(ws + off);                     // doubles as cursors
  off += ((VOCAB * 4 + 255) / 256) * 256;             // 400,128
  u32* offsets = (u32*)(ws + off);
  off += (((VOCAB + 1) * 4 + 255) / 256) * 256;       // 400,128
  u32* partials = (u32*)(ws + off);
  off += 4096;
  u32* pairs = (u32*)(ws + off);
  off += (size_t)NPAIRS * 4;                          // 3,276,800
  const size_t needed = off;                          // ~6.18 MB

  gelu_head_kernel<<<BDIM / 8, 256, 0, stream>>>(x, W_mu, b_mu, h);

  if (ws_size >= needed) {
    hipMemsetAsync(counts, 0, (size_t)VOCAB * 4, stream);
    hist_kernel<<<NPAIRS / 256, 256, 0, stream>>>(candidates, counts);
    scan1_kernel<<<NSB, 256, 0, stream>>>(counts, offsets, partials);
    scan2_kernel<<<1, 256, 0, stream>>>(partials);
    scan_add_kernel<<<(VOCAB + 256) / 256, 256, 0, stream>>>(offsets, partials, counts);
    scatter_kernel<<<NPAIRS / 256, 256, 0, stream>>>(candidates, counts, pairs);
    vocab_dot_kernel<<<(VOCAB * 64) / 256, 256, 0, stream>>>(h, emb_table, mu_bias,
                                                             offsets, pairs, out);
  } else {
    gather_dot_kernel<<<(BDIM * 2) / 4, 256, 0, stream>>>(h, candidates, mu_bias,
                                                          emb_table, out);
  }
}